// Round 1
// baseline (221.396 us; speedup 1.0000x reference)
//
#include <hip/hip_runtime.h>
#include <hip/hip_cooperative_groups.h>
#include <math.h>

namespace cg = cooperative_groups;

#define B 8
#define NPTS 4096
#define QPT 8           // queries per thread in chamfer
#define THREADS 256

__device__ __forceinline__ float min3f(float a, float b, float c) {
  // nested form so ISel fuses to v_min3_f32
  return fminf(fminf(a, b), c);
}

// ws layout: [partial: 2*B*S*NPTS f][sums32: 32 f][h1p: 64*256 f][h2p: 16*128 f]
// partial[((dir*B+b)*S + split)*NPTS + q]
// sums32[(dir*B+b)*2 + {0:min,1:soft}]  (atomic-accumulated in phase B)

// ======================= fused cooperative kernel =======================
template<int S, int LOG2S>
__global__ __launch_bounds__(THREADS, 4) void fused_kernel(
    const float* __restrict__ pred, const float* __restrict__ targ,
    const float* __restrict__ x, const float* __restrict__ W1,
    const float* __restrict__ b1, const float* __restrict__ W2,
    const float* __restrict__ b2, const float* __restrict__ W3,
    const float* __restrict__ b3, const int* __restrict__ labels,
    const float* __restrict__ wgt,
    float* __restrict__ partial, float* __restrict__ sums32,
    float* __restrict__ h1p, float* __restrict__ h2p,
    float* __restrict__ out) {
  constexpr int REFS = NPTS / S;
  cg::grid_group grid = cg::this_grid();
  const int tid = threadIdx.x;

  __shared__ float4 refs[REFS];
  __shared__ float xs[64];
  __shared__ float hs[128];
  __shared__ float red[8];
  __shared__ float h2s[8 * 128];
  __shared__ float lg[48];
  __shared__ float nlls[8];

  // ---- Phase A1: MLP layer-1 partials (+ sums32 init by block owning id 0)
  for (int id = blockIdx.x; id < 64; id += gridDim.x) {
    if (id == 0 && tid < 32) sums32[tid] = 0.f;
    int b = id >> 3, kc = id & 7;
    if (tid < 64) xs[tid] = x[b * 512 + kc * 64 + tid];
    __syncthreads();
    float acc = 0.f;
    const float* w = W1 + (size_t)(kc * 64) * 256 + tid;
#pragma unroll 8
    for (int k = 0; k < 64; ++k) acc = fmaf(xs[k], w[k * 256], acc);
    h1p[(b * 8 + kc) * 256 + tid] = acc;
    __syncthreads();
  }

  // ---- Phase A2: chamfer split-partial mins
  for (int cid = blockIdx.x; cid < 32 * S; cid += gridDim.x) {
    int split  = cid & (S - 1);
    int qchunk = (cid >> LOG2S) & 1;
    int b      = (cid >> (LOG2S + 1)) & 7;
    int dir    = cid >> (LOG2S + 4);
    const float* qp = dir ? targ : pred;
    const float* rp = dir ? pred : targ;

    const float* rb = rp + ((size_t)b * NPTS + (size_t)split * REFS) * 3;
    for (int i = tid; i < REFS; i += THREADS) {
      float xx = rb[i * 3 + 0], yy = rb[i * 3 + 1], zz = rb[i * 3 + 2];
      refs[i] = make_float4(xx, yy, zz, 0.5f * (xx * xx + yy * yy + zz * zz));
    }
    __syncthreads();

    const float* qb = qp + (size_t)b * NPTS * 3;
    int q0 = qchunk * (QPT * THREADS) + tid;
    float qx[QPT], qy[QPT], qz[QPT], vmin[QPT];
#pragma unroll
    for (int i = 0; i < QPT; ++i) {
      int q = q0 + i * THREADS;
      qx[i] = qb[q * 3 + 0];
      qy[i] = qb[q * 3 + 1];
      qz[i] = qb[q * 3 + 2];
      vmin[i] = 3.4e38f;
    }

    for (int j = 0; j < REFS; j += 8) {
      float4 t[8];
#pragma unroll
      for (int u = 0; u < 8; ++u) t[u] = refs[j + u];
#pragma unroll
      for (int i = 0; i < QPT; ++i) {
        float s[8];
#pragma unroll
        for (int u = 0; u < 8; ++u)
          s[u] = fmaf(-qx[i], t[u].x,
                 fmaf(-qy[i], t[u].y, fmaf(-qz[i], t[u].z, t[u].w)));
        float m0 = min3f(s[0], s[1], s[2]);
        float m1 = min3f(s[3], s[4], s[5]);
        float m2 = min3f(s[6], s[7], m0);
        vmin[i] = min3f(m1, m2, vmin[i]);
      }
    }

    size_t base = (((size_t)dir * B + b) * S + split) * NPTS;
#pragma unroll
    for (int i = 0; i < QPT; ++i) {
      float qn = fmaf(qx[i], qx[i], fmaf(qy[i], qy[i], qz[i] * qz[i]));
      partial[base + q0 + i * THREADS] = fmaf(2.f, vmin[i], qn);
    }
    __syncthreads();   // protect refs[] for next grid-stride iteration
  }

  grid.sync();

  // ---- Phase B: reduce over splits (256 items) + MLP L2 partials (16 items)
  for (int id = blockIdx.x; id < 272; id += gridDim.x) {
    if (id >= 256) {
      int lid = id - 256;
      int b = lid >> 1, half = lid & 1;
      if (tid < 128) {
        int k = half * 128 + tid;
        float a = b1[k];
#pragma unroll
        for (int p = 0; p < 8; ++p) a += h1p[(b * 8 + p) * 256 + k];
        hs[tid] = fmaxf(a, 0.f);
      }
      __syncthreads();
      if (tid < 128) {
        float acc = 0.f;
        const float* w = W2 + (size_t)(half * 128) * 128 + tid;
#pragma unroll 8
        for (int k = 0; k < 128; ++k) acc = fmaf(hs[k], w[k * 128], acc);
        h2p[(b * 2 + half) * 128 + tid] = acc;
      }
      __syncthreads();
    } else {
      int chunk = id & 15;
      int b   = (id >> 4) & 7;
      int dir = id >> 7;
      size_t pb = ((size_t)dir * B + b) * S * NPTS;
      int q = chunk * 256 + tid;

      float m = 3.4e38f;
#pragma unroll
      for (int s = 0; s < S; ++s)
        m = fminf(m, partial[pb + (size_t)s * NPTS + q]);
      float s_min = m;
      float s_soft = __expf(-5000.0f * m);   // 1/(2*sigma^2) = 5000

      for (int off = 32; off > 0; off >>= 1) {
        s_min  += __shfl_down(s_min,  off);
        s_soft += __shfl_down(s_soft, off);
      }
      int wave = tid >> 6, lane = tid & 63;
      if (lane == 0) { red[wave * 2] = s_min; red[wave * 2 + 1] = s_soft; }
      __syncthreads();
      if (tid == 0) {
        float a = 0.f, c = 0.f;
        for (int wv = 0; wv < 4; ++wv) { a += red[wv * 2]; c += red[wv * 2 + 1]; }
        atomicAdd(&sums32[(dir * B + b) * 2 + 0], a);
        atomicAdd(&sums32[(dir * B + b) * 2 + 1], c);
      }
      __syncthreads();
    }
  }

  grid.sync();

  // ---- Phase C: L2 combine + L3 + softmax/NLL + final combine (block 0)
  if (blockIdx.x == 0) {
    for (int i = tid; i < 1024; i += THREADS) {
      int b = i >> 7, j = i & 127;
      float a = b2[j] + h2p[(b * 2 + 0) * 128 + j] + h2p[(b * 2 + 1) * 128 + j];
      h2s[i] = fmaxf(a, 0.f);
    }
    __syncthreads();
    if (tid < 48) {
      int b = tid / 6, d = tid % 6;
      float acc = b3[d];
#pragma unroll 8
      for (int k = 0; k < 128; ++k) acc = fmaf(h2s[b * 128 + k], W3[k * 6 + d], acc);
      lg[tid] = acc;
    }
    __syncthreads();
    if (tid < 8) {
      int b = tid;
      float mx = lg[b * 6];
      for (int d = 1; d < 6; ++d) mx = fmaxf(mx, lg[b * 6 + d]);
      float se = 0.f;
      for (int d = 0; d < 6; ++d) se += __expf(lg[b * 6 + d] - mx);
      int lab = labels[b];
      nlls[b] = -(lg[b * 6 + lab] - mx - __logf(se));
    }
    __syncthreads();
    if (tid == 0) {
      float chamfer = 0.f, prec = 0.f, rec = 0.f, dsw = 0.f, dom = 0.f;
      for (int b = 0; b < B; ++b) {
        float sa  = sums32[(0 * B + b) * 2 + 0];
        float ssa = sums32[(0 * B + b) * 2 + 1];
        float sb  = sums32[(1 * B + b) * 2 + 0];
        float ssb = sums32[(1 * B + b) * 2 + 1];
        float ma = sa / 4096.f, mb = sb / 4096.f;
        float p = ssa / 4096.f, r = ssb / 4096.f;
        chamfer += ma + mb;
        prec += p; rec += r;
        float f_i = 2.f * p * r / (p + r + 1e-8f);
        float loss_i = ma + mb + 0.1f * (1.f - f_i);
        dsw += wgt[b] * loss_i;
        dom += nlls[b];
      }
      chamfer *= (1.f / B); prec *= (1.f / B); rec *= (1.f / B);
      dsw *= (1.f / B); dom *= (1.f / B);
      float fscore = 2.f * prec * rec / (prec + rec + 1e-8f);
      float task = chamfer + 0.1f * (1.f - fscore);
      out[0] = 1.0f * task + 0.1f * dom + dsw;
    }
  }
}

// ======================= fallback 3-kernel pipeline =====================
template<int S, int LOG2S>
__global__ __launch_bounds__(THREADS, 4) void d1_kernel(
    const float* __restrict__ pred, const float* __restrict__ targ,
    const float* __restrict__ x, const float* __restrict__ W1,
    float* __restrict__ partial, float* __restrict__ sums32,
    float* __restrict__ h1p) {
  constexpr int REFS = NPTS / S;
  int id = blockIdx.x;
  int tid = threadIdx.x;

  __shared__ float4 refs[REFS];
  __shared__ float xs[64];

  if (id < 64) {
    if (id == 0 && tid < 32) sums32[tid] = 0.f;
    int b = id >> 3, kc = id & 7;
    if (tid < 64) xs[tid] = x[b * 512 + kc * 64 + tid];
    __syncthreads();
    float acc = 0.f;
    const float* w = W1 + (size_t)(kc * 64) * 256 + tid;
#pragma unroll 8
    for (int k = 0; k < 64; ++k) acc = fmaf(xs[k], w[k * 256], acc);
    h1p[(b * 8 + kc) * 256 + tid] = acc;
    return;
  }

  int cid = id - 64;
  int split  = cid & (S - 1);
  int qchunk = (cid >> LOG2S) & 1;
  int b      = (cid >> (LOG2S + 1)) & 7;
  int dir    = cid >> (LOG2S + 4);
  const float* qp = dir ? targ : pred;
  const float* rp = dir ? pred : targ;

  const float* rb = rp + ((size_t)b * NPTS + (size_t)split * REFS) * 3;
  for (int i = tid; i < REFS; i += THREADS) {
    float xx = rb[i * 3 + 0], yy = rb[i * 3 + 1], zz = rb[i * 3 + 2];
    refs[i] = make_float4(xx, yy, zz, 0.5f * (xx * xx + yy * yy + zz * zz));
  }
  __syncthreads();

  const float* qb = qp + (size_t)b * NPTS * 3;
  int q0 = qchunk * (QPT * THREADS) + tid;
  float qx[QPT], qy[QPT], qz[QPT], vmin[QPT];
#pragma unroll
  for (int i = 0; i < QPT; ++i) {
    int q = q0 + i * THREADS;
    qx[i] = qb[q * 3 + 0];
    qy[i] = qb[q * 3 + 1];
    qz[i] = qb[q * 3 + 2];
    vmin[i] = 3.4e38f;
  }

  for (int j = 0; j < REFS; j += 8) {
    float4 t[8];
#pragma unroll
    for (int u = 0; u < 8; ++u) t[u] = refs[j + u];
#pragma unroll
    for (int i = 0; i < QPT; ++i) {
      float s[8];
#pragma unroll
      for (int u = 0; u < 8; ++u)
        s[u] = fmaf(-qx[i], t[u].x,
               fmaf(-qy[i], t[u].y, fmaf(-qz[i], t[u].z, t[u].w)));
      float m0 = min3f(s[0], s[1], s[2]);
      float m1 = min3f(s[3], s[4], s[5]);
      float m2 = min3f(s[6], s[7], m0);
      vmin[i] = min3f(m1, m2, vmin[i]);
    }
  }

  size_t base = (((size_t)dir * B + b) * S + split) * NPTS;
#pragma unroll
  for (int i = 0; i < QPT; ++i) {
    float qn = fmaf(qx[i], qx[i], fmaf(qy[i], qy[i], qz[i] * qz[i]));
    partial[base + q0 + i * THREADS] = fmaf(2.f, vmin[i], qn);
  }
}

template<int S>
__global__ __launch_bounds__(THREADS) void d2_kernel(
    const float* __restrict__ partial, float* __restrict__ sums32,
    const float* __restrict__ h1p, const float* __restrict__ b1,
    const float* __restrict__ W2, float* __restrict__ h2p) {
  int id = blockIdx.x;
  int tid = threadIdx.x;

  if (id >= 256) {
    int lid = id - 256;
    int b = lid >> 1, half = lid & 1;
    __shared__ float hs[128];
    if (tid < 128) {
      int k = half * 128 + tid;
      float a = b1[k];
#pragma unroll
      for (int p = 0; p < 8; ++p) a += h1p[(b * 8 + p) * 256 + k];
      hs[tid] = fmaxf(a, 0.f);
    }
    __syncthreads();
    if (tid < 128) {
      float acc = 0.f;
      const float* w = W2 + (size_t)(half * 128) * 128 + tid;
#pragma unroll 8
      for (int k = 0; k < 128; ++k) acc = fmaf(hs[k], w[k * 128], acc);
      h2p[(b * 2 + half) * 128 + tid] = acc;
    }
    return;
  }

  int chunk = id & 15;
  int b   = (id >> 4) & 7;
  int dir = id >> 7;
  size_t pb = ((size_t)dir * B + b) * S * NPTS;
  int q = chunk * 256 + tid;

  float m = 3.4e38f;
#pragma unroll
  for (int s = 0; s < S; ++s)
    m = fminf(m, partial[pb + (size_t)s * NPTS + q]);
  float s_min = m;
  float s_soft = __expf(-5000.0f * m);

  for (int off = 32; off > 0; off >>= 1) {
    s_min  += __shfl_down(s_min,  off);
    s_soft += __shfl_down(s_soft, off);
  }
  __shared__ float red[8];
  int wave = tid >> 6, lane = tid & 63;
  if (lane == 0) { red[wave * 2] = s_min; red[wave * 2 + 1] = s_soft; }
  __syncthreads();
  if (tid == 0) {
    float a = 0.f, c = 0.f;
    for (int w = 0; w < 4; ++w) { a += red[w * 2]; c += red[w * 2 + 1]; }
    atomicAdd(&sums32[(dir * B + b) * 2 + 0], a);
    atomicAdd(&sums32[(dir * B + b) * 2 + 1], c);
  }
}

__global__ __launch_bounds__(THREADS) void final_kernel(
    const float* __restrict__ h2p, const float* __restrict__ b2,
    const float* __restrict__ W3, const float* __restrict__ b3,
    const int* __restrict__ labels, const float* __restrict__ sums32,
    const float* __restrict__ w, float* __restrict__ out) {
  int tid = threadIdx.x;
  __shared__ float h2s[8 * 128];
  __shared__ float lg[48];
  __shared__ float nlls[8];

  for (int i = tid; i < 1024; i += THREADS) {
    int b = i >> 7, j = i & 127;
    float a = b2[j] + h2p[(b * 2 + 0) * 128 + j] + h2p[(b * 2 + 1) * 128 + j];
    h2s[i] = fmaxf(a, 0.f);
  }
  __syncthreads();
  if (tid < 48) {
    int b = tid / 6, d = tid % 6;
    float acc = b3[d];
#pragma unroll 8
    for (int k = 0; k < 128; ++k) acc = fmaf(h2s[b * 128 + k], W3[k * 6 + d], acc);
    lg[tid] = acc;
  }
  __syncthreads();
  if (tid < 8) {
    int b = tid;
    float mx = lg[b * 6];
    for (int d = 1; d < 6; ++d) mx = fmaxf(mx, lg[b * 6 + d]);
    float se = 0.f;
    for (int d = 0; d < 6; ++d) se += __expf(lg[b * 6 + d] - mx);
    int lab = labels[b];
    nlls[b] = -(lg[b * 6 + lab] - mx - __logf(se));
  }
  __syncthreads();
  if (tid == 0) {
    float chamfer = 0.f, prec = 0.f, rec = 0.f, dsw = 0.f, dom = 0.f;
    for (int b = 0; b < B; ++b) {
      float sa  = sums32[(0 * B + b) * 2 + 0];
      float ssa = sums32[(0 * B + b) * 2 + 1];
      float sb  = sums32[(1 * B + b) * 2 + 0];
      float ssb = sums32[(1 * B + b) * 2 + 1];
      float ma = sa / 4096.f, mb = sb / 4096.f;
      float p = ssa / 4096.f, r = ssb / 4096.f;
      chamfer += ma + mb;
      prec += p; rec += r;
      float f_i = 2.f * p * r / (p + r + 1e-8f);
      float loss_i = ma + mb + 0.1f * (1.f - f_i);
      dsw += w[b] * loss_i;
      dom += nlls[b];
    }
    chamfer *= (1.f / B); prec *= (1.f / B); rec *= (1.f / B);
    dsw *= (1.f / B); dom *= (1.f / B);
    float fscore = 2.f * prec * rec / (prec + rec + 1e-8f);
    float task = chamfer + 0.1f * (1.f - fscore);
    out[0] = 1.0f * task + 0.1f * dom + dsw;
  }
}

// ======================= host dispatch ==================================
template<int S, int LOG2S>
static void run_pipeline(const float* pred, const float* targ, const float* x,
                         const float* wgt, const float* W1, const float* b1,
                         const float* W2, const float* b2, const float* W3,
                         const float* b3, const int* labels, float* out,
                         char* ws, hipStream_t stream) {
  float* partial = (float*)ws;
  float* sums32  = partial + (size_t)2 * B * S * NPTS;
  float* h1p     = sums32 + 32;
  float* h2p     = h1p + 64 * 256;

  // grid size for cooperative launch: co-resident capacity, capped at 1024
  // (S=32: 1024 chamfer slices map 1:1; MLP items ride on blocks 0..63)
  static int g_blocks = 0;
  if (g_blocks == 0) {
    int dev = 0;
    (void)hipGetDevice(&dev);
    hipDeviceProp_t props;
    int ncu = 256;
    if (hipGetDeviceProperties(&props, dev) == hipSuccess &&
        props.multiProcessorCount > 0)
      ncu = props.multiProcessorCount;
    int maxb = 0;
    if (hipOccupancyMaxActiveBlocksPerMultiprocessor(
            &maxb, fused_kernel<S, LOG2S>, THREADS, 0) != hipSuccess ||
        maxb <= 0)
      maxb = 2;   // conservative: 2 blocks/CU always fits (<=256 VGPR, ~9KB LDS)
    long g = (long)maxb * ncu;
    if (g > 1024) g = 1024;
    if (g < 64) g = 64;
    g_blocks = (int)g;
  }

  void* args[] = {(void*)&pred, (void*)&targ, (void*)&x,    (void*)&W1,
                  (void*)&b1,   (void*)&W2,   (void*)&b2,   (void*)&W3,
                  (void*)&b3,   (void*)&labels, (void*)&wgt,
                  (void*)&partial, (void*)&sums32, (void*)&h1p,
                  (void*)&h2p,  (void*)&out};
  hipError_t e = hipLaunchCooperativeKernel(fused_kernel<S, LOG2S>,
                                            dim3(g_blocks), dim3(THREADS),
                                            args, 0, stream);
  if (e != hipSuccess) {
    (void)hipGetLastError();   // clear sticky error; fall back to 3 kernels
    hipLaunchKernelGGL((d1_kernel<S, LOG2S>), dim3(64 + 32 * S), dim3(THREADS),
                       0, stream, pred, targ, x, W1, partial, sums32, h1p);
    hipLaunchKernelGGL((d2_kernel<S>), dim3(256 + 16), dim3(THREADS), 0, stream,
                       partial, sums32, h1p, b1, W2, h2p);
    hipLaunchKernelGGL(final_kernel, dim3(1), dim3(THREADS), 0, stream,
                       h2p, b2, W3, b3, labels, sums32, wgt, out);
  }
}

extern "C" void kernel_launch(void* const* d_in, const int* in_sizes, int n_in,
                              void* d_out, int out_size, void* d_ws, size_t ws_size,
                              hipStream_t stream) {
  const float* pred   = (const float*)d_in[0];
  const float* targ   = (const float*)d_in[1];
  const float* x      = (const float*)d_in[2];
  const float* wgt    = (const float*)d_in[3];
  const float* W1     = (const float*)d_in[4];
  const float* b1     = (const float*)d_in[5];
  const float* W2     = (const float*)d_in[6];
  const float* b2     = (const float*)d_in[7];
  const float* W3     = (const float*)d_in[8];
  const float* b3     = (const float*)d_in[9];
  const int*   labels = (const int*)d_in[10];
  float* out = (float*)d_out;
  char* ws = (char*)d_ws;

  auto need = [](int S) {
    return ((size_t)2 * B * S * NPTS + 32 + 64 * 256 + 16 * 128) * sizeof(float);
  };
  if (ws_size >= need(32))
    run_pipeline<32, 5>(pred, targ, x, wgt, W1, b1, W2, b2, W3, b3, labels,
                        out, ws, stream);
  else if (ws_size >= need(16))
    run_pipeline<16, 4>(pred, targ, x, wgt, W1, b1, W2, b2, W3, b3, labels,
                        out, ws, stream);
  else
    run_pipeline<8, 3>(pred, targ, x, wgt, W1, b1, W2, b2, W3, b3, labels,
                       out, ws, stream);
}

// Round 3
// 137.375 us; speedup vs baseline: 1.6116x; 1.6116x over previous
//
#include <hip/hip_runtime.h>
#include <math.h>

#define B 8
#define NPTS 4096
#define QPT 8           // queries per thread in chamfer
#define THREADS 256

typedef float v2f __attribute__((ext_vector_type(2)));
typedef float v4f __attribute__((ext_vector_type(4)));

__device__ __forceinline__ float min3f(float a, float b, float c) {
  return fminf(fminf(a, b), c);   // fuses to v_min3_f32
}

#if __has_builtin(__builtin_elementwise_fma)
__device__ __forceinline__ v2f fma2(v2f a, v2f b, v2f c) {
  return __builtin_elementwise_fma(a, b, c);   // -> v_pk_fma_f32
}
#else
__device__ __forceinline__ v2f fma2(v2f a, v2f b, v2f c) {
  v2f r; r.x = __builtin_fmaf(a.x, b.x, c.x); r.y = __builtin_fmaf(a.y, b.y, c.y);
  return r;
}
#endif

#define VLO(v) __builtin_shufflevector(v, v, 0, 1)
#define VHI(v) __builtin_shufflevector(v, v, 2, 3)

// ws layout: [partial: 2*B*S*NPTS f][sums64: 64 f][h1p: 64*256 f]
// partial[((dir*B+b)*S + split)*NPTS + q]
// sums64[(dir*B+b)*2 + {0:min,1:soft}]; sums64[32] = done-counter (as u32)

// ======== K1: chamfer split-partial mins (+ MLP-L1 partials on blocks 0..63)
template<int S, int LOG2S>
__global__ __launch_bounds__(THREADS, 4) void k1_kernel(
    const float* __restrict__ pred, const float* __restrict__ targ,
    const float* __restrict__ x, const float* __restrict__ W1,
    float* __restrict__ partial, float* __restrict__ sums64,
    float* __restrict__ h1p) {
  constexpr int REFS = NPTS / S;
  const int tid = threadIdx.x;
  const int cid = blockIdx.x;

  __shared__ __align__(16) float sx[REFS];
  __shared__ __align__(16) float sy[REFS];
  __shared__ __align__(16) float sz[REFS];
  __shared__ __align__(16) float sw[REFS];
  __shared__ float xs[64];

  if (cid < 64) {
    // MLP layer-1 partials: h1p[(b*8+kc)*256+j] = sum_{k in chunk} x[b,k]W1[k,j]
    if (cid == 0 && tid < 64) sums64[tid] = 0.f;   // zero sums + done-counter
    int b = cid >> 3, kc = cid & 7;
    if (tid < 64) xs[tid] = x[b * 512 + kc * 64 + tid];
    __syncthreads();
    float acc = 0.f;
    const float* w = W1 + (size_t)(kc * 64) * 256 + tid;
#pragma unroll 8
    for (int k = 0; k < 64; ++k) acc = fmaf(xs[k], w[k * 256], acc);
    h1p[(b * 8 + kc) * 256 + tid] = acc;
  }

  // ---- chamfer: every block handles one (dir,b,qchunk,split) slice
  int split  = cid & (S - 1);
  int qchunk = (cid >> LOG2S) & 1;
  int b      = (cid >> (LOG2S + 1)) & 7;
  int dir    = cid >> (LOG2S + 4);
  const float* qp = dir ? targ : pred;
  const float* rp = dir ? pred : targ;

  const float* rb = rp + ((size_t)b * NPTS + (size_t)split * REFS) * 3;
  for (int i = tid; i < REFS; i += THREADS) {
    float xx = rb[i * 3 + 0], yy = rb[i * 3 + 1], zz = rb[i * 3 + 2];
    sx[i] = xx; sy[i] = yy; sz[i] = zz;
    sw[i] = 0.5f * (xx * xx + yy * yy + zz * zz);
  }
  __syncthreads();

  const float* qb = qp + (size_t)b * NPTS * 3;
  int q0 = qchunk * (QPT * THREADS) + tid;
  float qx[QPT], qy[QPT], qz[QPT], vmin[QPT];
#pragma unroll
  for (int i = 0; i < QPT; ++i) {
    int q = q0 + i * THREADS;
    qx[i] = qb[q * 3 + 0];
    qy[i] = qb[q * 3 + 1];
    qz[i] = qb[q * 3 + 2];
    vmin[i] = 3.4e38f;
  }

  for (int j = 0; j < REFS; j += 8) {
    v4f xA = *(const v4f*)(sx + j), xB = *(const v4f*)(sx + j + 4);
    v4f yA = *(const v4f*)(sy + j), yB = *(const v4f*)(sy + j + 4);
    v4f zA = *(const v4f*)(sz + j), zB = *(const v4f*)(sz + j + 4);
    v4f wA = *(const v4f*)(sw + j), wB = *(const v4f*)(sw + j + 4);
    v2f x01 = VLO(xA), x23 = VHI(xA), x45 = VLO(xB), x67 = VHI(xB);
    v2f y01 = VLO(yA), y23 = VHI(yA), y45 = VLO(yB), y67 = VHI(yB);
    v2f z01 = VLO(zA), z23 = VHI(zA), z45 = VLO(zB), z67 = VHI(zB);
    v2f w01 = VLO(wA), w23 = VHI(wA), w45 = VLO(wB), w67 = VHI(wB);
#pragma unroll
    for (int i = 0; i < QPT; ++i) {
      v2f nx = {-qx[i], -qx[i]};
      v2f ny = {-qy[i], -qy[i]};
      v2f nz = {-qz[i], -qz[i]};
      // s = -qx*tx + (-qy*ty + (-qz*tz + 0.5|t|^2))  (same fma order as before)
      v2f s01 = fma2(nx, x01, fma2(ny, y01, fma2(nz, z01, w01)));
      v2f s23 = fma2(nx, x23, fma2(ny, y23, fma2(nz, z23, w23)));
      v2f s45 = fma2(nx, x45, fma2(ny, y45, fma2(nz, z45, w45)));
      v2f s67 = fma2(nx, x67, fma2(ny, y67, fma2(nz, z67, w67)));
      float m0 = min3f(s01.x, s01.y, s23.x);
      float m1 = min3f(s23.y, s45.x, s45.y);
      float m2 = min3f(s67.x, s67.y, m0);
      vmin[i] = min3f(m1, m2, vmin[i]);
    }
  }

  size_t base = (((size_t)dir * B + b) * S + split) * NPTS;
#pragma unroll
  for (int i = 0; i < QPT; ++i) {
    float qn = fmaf(qx[i], qx[i], fmaf(qy[i], qy[i], qz[i] * qz[i]));
    partial[base + q0 + i * THREADS] = fmaf(2.f, vmin[i], qn);
  }
}

// ======== K2: reduce over splits; LAST block finishes MLP + final combine
template<int S>
__global__ __launch_bounds__(THREADS) void k2_kernel(
    const float* __restrict__ partial, float* __restrict__ sums64,
    const float* __restrict__ h1p, const float* __restrict__ b1,
    const float* __restrict__ W2, const float* __restrict__ b2,
    const float* __restrict__ W3, const float* __restrict__ b3,
    const int* __restrict__ labels, const float* __restrict__ wgt,
    float* __restrict__ out) {
  const int id = blockIdx.x;   // 0..255
  const int tid = threadIdx.x;
  __shared__ float red[8];
  __shared__ bool is_last;

  // ---- reduce: min over S splits, sum min and exp
  int chunk = id & 15;
  int b   = (id >> 4) & 7;
  int dir = id >> 7;
  size_t pb = ((size_t)dir * B + b) * S * NPTS;
  int q = chunk * 256 + tid;

  float m = 3.4e38f;
#pragma unroll
  for (int s = 0; s < S; ++s)
    m = fminf(m, partial[pb + (size_t)s * NPTS + q]);
  float s_min = m;
  float s_soft = __expf(-5000.0f * m);   // 1/(2*sigma^2) = 5000

  for (int off = 32; off > 0; off >>= 1) {
    s_min  += __shfl_down(s_min,  off);
    s_soft += __shfl_down(s_soft, off);
  }
  int wave = tid >> 6, lane = tid & 63;
  if (lane == 0) { red[wave * 2] = s_min; red[wave * 2 + 1] = s_soft; }
  __syncthreads();
  if (tid == 0) {
    float a = 0.f, c = 0.f;
    for (int wv = 0; wv < 4; ++wv) { a += red[wv * 2]; c += red[wv * 2 + 1]; }
    atomicAdd(&sums64[(dir * B + b) * 2 + 0], a);
    atomicAdd(&sums64[(dir * B + b) * 2 + 1], c);
    __threadfence();                                   // release our adds
    unsigned t = atomicAdd((unsigned*)(sums64 + 32), 1u);
    is_last = (t == 255u);
  }
  __syncthreads();
  if (!is_last) return;
  __threadfence();                                     // acquire side

  // ---- tail (one block): L1 combine + L2 + L3 + softmax/NLL + final
  __shared__ float h1s[8 * 256];
  __shared__ float h2s[8 * 128];
  __shared__ float lg[48];
  __shared__ float nlls[8];

  for (int i = tid; i < 2048; i += THREADS) {
    int bb = i >> 8, k = i & 255;
    float a = b1[k];
#pragma unroll
    for (int p = 0; p < 8; ++p) a += h1p[(bb * 8 + p) * 256 + k];
    h1s[i] = fmaxf(a, 0.f);
  }
  __syncthreads();
  for (int i = tid; i < 1024; i += THREADS) {
    int bb = i >> 7, jo = i & 127;
    float acc = b2[jo];
    const float* w2 = W2 + jo;
    const float* h1r = h1s + bb * 256;
#pragma unroll 8
    for (int k = 0; k < 256; ++k) acc = fmaf(h1r[k], w2[(size_t)k * 128], acc);
    h2s[i] = fmaxf(acc, 0.f);
  }
  __syncthreads();
  if (tid < 48) {
    int bb = tid / 6, d = tid % 6;
    float acc = b3[d];
#pragma unroll 8
    for (int k = 0; k < 128; ++k)
      acc = fmaf(h2s[bb * 128 + k], W3[k * 6 + d], acc);
    lg[tid] = acc;
  }
  __syncthreads();
  if (tid < 8) {
    int bb = tid;
    float mx = lg[bb * 6];
    for (int d = 1; d < 6; ++d) mx = fmaxf(mx, lg[bb * 6 + d]);
    float se = 0.f;
    for (int d = 0; d < 6; ++d) se += __expf(lg[bb * 6 + d] - mx);
    int lab = labels[bb];
    nlls[bb] = -(lg[bb * 6 + lab] - mx - __logf(se));
  }
  __syncthreads();
  if (tid == 0) {
    // all 256 block-adds are ordered before us via the done-counter
    // (release fence + atomicAdd) and our acquire fence above; volatile
    // loads read the coherent values.
    volatile const float* vs = (volatile const float*)sums64;
    float chamfer = 0.f, prec = 0.f, rec = 0.f, dsw = 0.f, dom = 0.f;
    for (int bb = 0; bb < B; ++bb) {
      float sa  = vs[(0 * B + bb) * 2 + 0];
      float ssa = vs[(0 * B + bb) * 2 + 1];
      float sb  = vs[(1 * B + bb) * 2 + 0];
      float ssb = vs[(1 * B + bb) * 2 + 1];
      float ma = sa / 4096.f, mb = sb / 4096.f;
      float p = ssa / 4096.f, r = ssb / 4096.f;
      chamfer += ma + mb;
      prec += p; rec += r;
      float f_i = 2.f * p * r / (p + r + 1e-8f);
      float loss_i = ma + mb + 0.1f * (1.f - f_i);
      dsw += wgt[bb] * loss_i;
      dom += nlls[bb];
    }
    chamfer *= (1.f / B); prec *= (1.f / B); rec *= (1.f / B);
    dsw *= (1.f / B); dom *= (1.f / B);
    float fscore = 2.f * prec * rec / (prec + rec + 1e-8f);
    float task = chamfer + 0.1f * (1.f - fscore);
    out[0] = 1.0f * task + 0.1f * dom + dsw;
  }
}

// ======================= host dispatch ==================================
template<int S, int LOG2S>
static void run_pipeline(const float* pred, const float* targ, const float* x,
                         const float* wgt, const float* W1, const float* b1,
                         const float* W2, const float* b2, const float* W3,
                         const float* b3, const int* labels, float* out,
                         char* ws, hipStream_t stream) {
  float* partial = (float*)ws;
  float* sums64  = partial + (size_t)2 * B * S * NPTS;
  float* h1p     = sums64 + 64;

  hipLaunchKernelGGL((k1_kernel<S, LOG2S>), dim3(32 * S), dim3(THREADS),
                     0, stream, pred, targ, x, W1, partial, sums64, h1p);
  hipLaunchKernelGGL((k2_kernel<S>), dim3(256), dim3(THREADS), 0, stream,
                     partial, sums64, h1p, b1, W2, b2, W3, b3, labels, wgt,
                     out);
}

extern "C" void kernel_launch(void* const* d_in, const int* in_sizes, int n_in,
                              void* d_out, int out_size, void* d_ws, size_t ws_size,
                              hipStream_t stream) {
  const float* pred   = (const float*)d_in[0];
  const float* targ   = (const float*)d_in[1];
  const float* x      = (const float*)d_in[2];
  const float* wgt    = (const float*)d_in[3];
  const float* W1     = (const float*)d_in[4];
  const float* b1     = (const float*)d_in[5];
  const float* W2     = (const float*)d_in[6];
  const float* b2     = (const float*)d_in[7];
  const float* W3     = (const float*)d_in[8];
  const float* b3     = (const float*)d_in[9];
  const int*   labels = (const int*)d_in[10];
  float* out = (float*)d_out;
  char* ws = (char*)d_ws;

  auto need = [](int S) {
    return ((size_t)2 * B * S * NPTS + 64 + 64 * 256) * sizeof(float);
  };
  if (ws_size >= need(32))
    run_pipeline<32, 5>(pred, targ, x, wgt, W1, b1, W2, b2, W3, b3, labels,
                        out, ws, stream);
  else if (ws_size >= need(16))
    run_pipeline<16, 4>(pred, targ, x, wgt, W1, b1, W2, b2, W3, b3, labels,
                        out, ws, stream);
  else
    run_pipeline<8, 3>(pred, targ, x, wgt, W1, b1, W2, b2, W3, b3, labels,
                       out, ws, stream);
}

// Round 4
// 133.401 us; speedup vs baseline: 1.6596x; 1.0298x over previous
//
#include <hip/hip_runtime.h>
#include <math.h>

#define B 8
#define NPTS 4096
#define QPT 4           // queries per thread in chamfer
#define QC  4           // q-chunks = NPTS / (QPT*THREADS)
#define THREADS 256

typedef float v2f __attribute__((ext_vector_type(2)));
typedef float v4f __attribute__((ext_vector_type(4)));

__device__ __forceinline__ float min3f(float a, float b, float c) {
  return fminf(fminf(a, b), c);   // fuses to v_min3_f32
}

#if __has_builtin(__builtin_elementwise_fma)
__device__ __forceinline__ v2f fma2(v2f a, v2f b, v2f c) {
  return __builtin_elementwise_fma(a, b, c);   // -> v_pk_fma_f32
}
#else
__device__ __forceinline__ v2f fma2(v2f a, v2f b, v2f c) {
  v2f r; r.x = __builtin_fmaf(a.x, b.x, c.x); r.y = __builtin_fmaf(a.y, b.y, c.y);
  return r;
}
#endif

#define VLO(v) __builtin_shufflevector(v, v, 0, 1)
#define VHI(v) __builtin_shufflevector(v, v, 2, 3)

// ws layout: [partial: 2*B*S*NPTS f][sums64: 64 f][h1p: 64*256 f][h2p: 16*128 f]
// partial[((dir*B+b)*S + split)*NPTS + q]
// sums64[(dir*B+b)*2 + {0:min,1:soft}]; sums64[32] = done-counter (u32)

// ======== K1: chamfer split-partial mins (+ MLP-L1 riders on bid 0..63) ====
// grid = 64 groups * S blocks. XCD-bijective swizzle: bid = cs*(8*S) + s*8 + x
// puts all S split-blocks of one (dir,b,qchunk) group on one XCD (L2 reuse
// of the shared q-range).
template<int S, int LOG2S>
__global__ __launch_bounds__(THREADS, 4) void k1_kernel(
    const float* __restrict__ pred, const float* __restrict__ targ,
    const float* __restrict__ x, const float* __restrict__ W1,
    float* __restrict__ partial, float* __restrict__ sums64,
    float* __restrict__ h1p) {
  constexpr int REFS = NPTS / S;
  const int tid = threadIdx.x;
  const int bid = blockIdx.x;

  __shared__ __align__(16) float sx[REFS];
  __shared__ __align__(16) float sy[REFS];
  __shared__ __align__(16) float sz[REFS];
  __shared__ __align__(16) float sw[REFS];
  __shared__ float xs[64];

  if (bid < 64) {
    // MLP layer-1 partials: h1p[(b*8+kc)*256+j] = sum_{k in chunk} x[b,k]W1[k,j]
    if (bid == 0 && tid < 64) sums64[tid] = 0.f;   // zero sums + done-counter
    int b = bid >> 3, kc = bid & 7;
    if (tid < 64) xs[tid] = x[b * 512 + kc * 64 + tid];
    __syncthreads();
    float acc = 0.f;
    const float* w = W1 + (size_t)(kc * 64) * 256 + tid;
#pragma unroll 8
    for (int k = 0; k < 64; ++k) acc = fmaf(xs[k], w[k * 256], acc);
    h1p[(b * 8 + kc) * 256 + tid] = acc;
    __syncthreads();
  }

  // ---- decode (XCD swizzle): xcd = bid&7 stays fixed within a group
  int xcd  = bid & 7;
  int spl  = (bid >> 3) & (S - 1);
  int cs   = bid >> (3 + LOG2S);
  int gid  = cs * 8 + xcd;                 // 0..63
  int qc   = gid & (QC - 1);
  int b    = (gid >> 2) & 7;
  int dir  = gid >> 5;
  const float* qp = dir ? targ : pred;
  const float* rp = dir ? pred : targ;

  // ---- q loads first (latency hides under refs staging + barrier)
  const float* qb = qp + (size_t)b * NPTS * 3;
  int q0 = qc * (QPT * THREADS) + tid;
  float qx[QPT], qy[QPT], qz[QPT];
#pragma unroll
  for (int i = 0; i < QPT; ++i) {
    int q = q0 + i * THREADS;
    qx[i] = qb[q * 3 + 0];
    qy[i] = qb[q * 3 + 1];
    qz[i] = qb[q * 3 + 2];
  }

  // ---- stage refs (SoA) into LDS
  const float* rb = rp + ((size_t)b * NPTS + (size_t)spl * REFS) * 3;
  for (int i = tid; i < REFS; i += THREADS) {
    float xx = rb[i * 3 + 0], yy = rb[i * 3 + 1], zz = rb[i * 3 + 2];
    sx[i] = xx; sy[i] = yy; sz[i] = zz;
    sw[i] = 0.5f * (xx * xx + yy * yy + zz * zz);
  }

  // ---- per-q precompute: |q|^2, negated broadcasts (hoisted out of loop)
  float qn[QPT], vmin[QPT];
  v2f bx[QPT], by[QPT], bz[QPT];
#pragma unroll
  for (int i = 0; i < QPT; ++i) {
    qn[i] = fmaf(qx[i], qx[i], fmaf(qy[i], qy[i], qz[i] * qz[i]));
    bx[i] = (v2f){-qx[i], -qx[i]};
    by[i] = (v2f){-qy[i], -qy[i]};
    bz[i] = (v2f){-qz[i], -qz[i]};
    vmin[i] = 3.4e38f;
  }
  __syncthreads();

  // ---- inner loop: 8 refs/iter, pk_fma pairs; s = -q.t + 0.5|t|^2
  for (int j = 0; j < REFS; j += 8) {
    v4f xA = *(const v4f*)(sx + j), xB = *(const v4f*)(sx + j + 4);
    v4f yA = *(const v4f*)(sy + j), yB = *(const v4f*)(sy + j + 4);
    v4f zA = *(const v4f*)(sz + j), zB = *(const v4f*)(sz + j + 4);
    v4f wA = *(const v4f*)(sw + j), wB = *(const v4f*)(sw + j + 4);
    v2f x01 = VLO(xA), x23 = VHI(xA), x45 = VLO(xB), x67 = VHI(xB);
    v2f y01 = VLO(yA), y23 = VHI(yA), y45 = VLO(yB), y67 = VHI(yB);
    v2f z01 = VLO(zA), z23 = VHI(zA), z45 = VLO(zB), z67 = VHI(zB);
    v2f w01 = VLO(wA), w23 = VHI(wA), w45 = VLO(wB), w67 = VHI(wB);
#pragma unroll
    for (int i = 0; i < QPT; ++i) {
      v2f s01 = fma2(bx[i], x01, fma2(by[i], y01, fma2(bz[i], z01, w01)));
      v2f s23 = fma2(bx[i], x23, fma2(by[i], y23, fma2(bz[i], z23, w23)));
      v2f s45 = fma2(bx[i], x45, fma2(by[i], y45, fma2(bz[i], z45, w45)));
      v2f s67 = fma2(bx[i], x67, fma2(by[i], y67, fma2(bz[i], z67, w67)));
      float m0 = min3f(s01.x, s01.y, s23.x);
      float m1 = min3f(s23.y, s45.x, s45.y);
      float m2 = min3f(s67.x, s67.y, m0);
      vmin[i] = min3f(m1, m2, vmin[i]);
    }
  }

  size_t base = (((size_t)dir * B + b) * S + spl) * NPTS;
#pragma unroll
  for (int i = 0; i < QPT; ++i)
    partial[base + q0 + i * THREADS] = fmaf(2.f, vmin[i], qn[i]);
}

// ======== K2: 256 reduce blocks + 16 MLP-L2 blocks; last block -> final ====
template<int S>
__global__ __launch_bounds__(THREADS) void k2_kernel(
    const float* __restrict__ partial, float* __restrict__ sums64,
    const float* __restrict__ h1p, const float* __restrict__ b1,
    const float* __restrict__ W2, const float* __restrict__ b2,
    const float* __restrict__ W3, const float* __restrict__ b3,
    const int* __restrict__ labels, const float* __restrict__ wgt,
    float* __restrict__ out) {
  constexpr int NBLK = 272;
  const int id = blockIdx.x;
  const int tid = threadIdx.x;
  __shared__ float red[8];
  __shared__ float hs[128];
  __shared__ bool is_last;

  if (id >= 256) {
    // ---- MLP-L2 partials: h2p[(b*2+half)*128+j] over k in [half*128,+128)
    int lid = id - 256;
    int b = lid >> 1, half = lid & 1;
    if (tid < 128) {
      int k = half * 128 + tid;
      float a = b1[k];
#pragma unroll
      for (int p = 0; p < 8; ++p) a += h1p[(b * 8 + p) * 256 + k];
      hs[tid] = fmaxf(a, 0.f);
    }
    __syncthreads();
    if (tid < 128) {
      float acc = 0.f;
      const float* w = W2 + (size_t)(half * 128) * 128 + tid;
#pragma unroll 8
      for (int k = 0; k < 128; ++k) acc = fmaf(hs[k], w[k * 128], acc);
      // h2p lives right after h1p in ws (sums64+64+64*256)
      float* h2p = sums64 + 64 + 64 * 256;
      h2p[(b * 2 + half) * 128 + tid] = acc;
    }
  } else {
    // ---- reduce: min over S splits (batched loads), sum min and exp
    int chunk = id & 15;
    int b   = (id >> 4) & 7;
    int dir = id >> 7;
    size_t pb = ((size_t)dir * B + b) * S * NPTS;
    int q = chunk * 256 + tid;

    float v[S];
#pragma unroll
    for (int s = 0; s < S; ++s)
      v[s] = partial[pb + (size_t)s * NPTS + q];
    float m = v[0];
#pragma unroll
    for (int s = 1; s < S; ++s) m = fminf(m, v[s]);
    float s_min = m;
    float s_soft = __expf(-5000.0f * m);   // 1/(2*sigma^2) = 5000

    for (int off = 32; off > 0; off >>= 1) {
      s_min  += __shfl_down(s_min,  off);
      s_soft += __shfl_down(s_soft, off);
    }
    int wave = tid >> 6, lane = tid & 63;
    if (lane == 0) { red[wave * 2] = s_min; red[wave * 2 + 1] = s_soft; }
    __syncthreads();
    if (tid == 0) {
      float a = 0.f, c = 0.f;
      for (int wv = 0; wv < 4; ++wv) { a += red[wv * 2]; c += red[wv * 2 + 1]; }
      atomicAdd(&sums64[(dir * B + b) * 2 + 0], a);
      atomicAdd(&sums64[(dir * B + b) * 2 + 1], c);
    }
  }

  // ---- done-counter handshake (stores -> fence(all) -> sync -> counter)
  __threadfence();
  __syncthreads();
  if (tid == 0) {
    unsigned t = atomicAdd((unsigned*)(sums64 + 32), 1u);
    is_last = (t == NBLK - 1);
  }
  __syncthreads();
  if (!is_last) return;
  __threadfence();                                   // acquire side

  // ---- tail (last block): L2-combine + L3 + softmax/NLL + final combine
  __shared__ float h2s[8 * 128];
  __shared__ float lg[48];
  __shared__ float nlls[8];
  volatile const float* vh2 = (volatile const float*)(sums64 + 64 + 64 * 256);

  for (int i = tid; i < 1024; i += THREADS) {
    int bb = i >> 7, j = i & 127;
    float a = b2[j] + vh2[(bb * 2 + 0) * 128 + j] + vh2[(bb * 2 + 1) * 128 + j];
    h2s[i] = fmaxf(a, 0.f);
  }
  __syncthreads();
  if (tid < 48) {
    int bb = tid / 6, d = tid % 6;
    float acc = b3[d];
#pragma unroll 8
    for (int k = 0; k < 128; ++k)
      acc = fmaf(h2s[bb * 128 + k], W3[k * 6 + d], acc);
    lg[tid] = acc;
  }
  __syncthreads();
  if (tid < 8) {
    int bb = tid;
    float mx = lg[bb * 6];
    for (int d = 1; d < 6; ++d) mx = fmaxf(mx, lg[bb * 6 + d]);
    float se = 0.f;
    for (int d = 0; d < 6; ++d) se += __expf(lg[bb * 6 + d] - mx);
    int lab = labels[bb];
    nlls[bb] = -(lg[bb * 6 + lab] - mx - __logf(se));
  }
  __syncthreads();
  if (tid == 0) {
    volatile const float* vs = (volatile const float*)sums64;
    float chamfer = 0.f, prec = 0.f, rec = 0.f, dsw = 0.f, dom = 0.f;
    for (int bb = 0; bb < B; ++bb) {
      float sa  = vs[(0 * B + bb) * 2 + 0];
      float ssa = vs[(0 * B + bb) * 2 + 1];
      float sb  = vs[(1 * B + bb) * 2 + 0];
      float ssb = vs[(1 * B + bb) * 2 + 1];
      float ma = sa / 4096.f, mb = sb / 4096.f;
      float p = ssa / 4096.f, r = ssb / 4096.f;
      chamfer += ma + mb;
      prec += p; rec += r;
      float f_i = 2.f * p * r / (p + r + 1e-8f);
      float loss_i = ma + mb + 0.1f * (1.f - f_i);
      dsw += wgt[bb] * loss_i;
      dom += nlls[bb];
    }
    chamfer *= (1.f / B); prec *= (1.f / B); rec *= (1.f / B);
    dsw *= (1.f / B); dom *= (1.f / B);
    float fscore = 2.f * prec * rec / (prec + rec + 1e-8f);
    float task = chamfer + 0.1f * (1.f - fscore);
    out[0] = 1.0f * task + 0.1f * dom + dsw;
  }
}

// ======================= host dispatch ==================================
template<int S, int LOG2S>
static void run_pipeline(const float* pred, const float* targ, const float* x,
                         const float* wgt, const float* W1, const float* b1,
                         const float* W2, const float* b2, const float* W3,
                         const float* b3, const int* labels, float* out,
                         char* ws, hipStream_t stream) {
  float* partial = (float*)ws;
  float* sums64  = partial + (size_t)2 * B * S * NPTS;
  float* h1p     = sums64 + 64;

  hipLaunchKernelGGL((k1_kernel<S, LOG2S>), dim3(64 * S), dim3(THREADS),
                     0, stream, pred, targ, x, W1, partial, sums64, h1p);
  hipLaunchKernelGGL((k2_kernel<S>), dim3(272), dim3(THREADS), 0, stream,
                     partial, sums64, h1p, b1, W2, b2, W3, b3, labels, wgt,
                     out);
}

extern "C" void kernel_launch(void* const* d_in, const int* in_sizes, int n_in,
                              void* d_out, int out_size, void* d_ws, size_t ws_size,
                              hipStream_t stream) {
  const float* pred   = (const float*)d_in[0];
  const float* targ   = (const float*)d_in[1];
  const float* x      = (const float*)d_in[2];
  const float* wgt    = (const float*)d_in[3];
  const float* W1     = (const float*)d_in[4];
  const float* b1     = (const float*)d_in[5];
  const float* W2     = (const float*)d_in[6];
  const float* b2     = (const float*)d_in[7];
  const float* W3     = (const float*)d_in[8];
  const float* b3     = (const float*)d_in[9];
  const int*   labels = (const int*)d_in[10];
  float* out = (float*)d_out;
  char* ws = (char*)d_ws;

  auto need = [](int S) {
    return ((size_t)2 * B * S * NPTS + 64 + 64 * 256 + 16 * 128) * sizeof(float);
  };
  if (ws_size >= need(32))
    run_pipeline<32, 5>(pred, targ, x, wgt, W1, b1, W2, b2, W3, b3, labels,
                        out, ws, stream);
  else if (ws_size >= need(16))
    run_pipeline<16, 4>(pred, targ, x, wgt, W1, b1, W2, b2, W3, b3, labels,
                        out, ws, stream);
  else
    run_pipeline<8, 3>(pred, targ, x, wgt, W1, b1, W2, b2, W3, b3, labels,
                       out, ws, stream);
}